// Round 7
// baseline (110.947 us; speedup 1.0000x reference)
//
#include <hip/hip_runtime.h>
#include <hip/hip_bf16.h>

#define IN_DIMX 135909
#define OUT_DIMX 670091
#define DDIM 128
#define BATCH 256
#define TFEAT 100
#define NBLK 768                      // 3 blocks/CU if VGPR<=170 (natural alloc), LDS 96KB/CU
#define NCHUNK ((OUT_DIMX + 63) / 64) // 10471 chunks of 64 classes
#define LOG2E 1.44269504088896f

typedef __bf16 bf16_t;
typedef __attribute__((ext_vector_type(8))) __bf16 bf16x8;
typedef __attribute__((ext_vector_type(4))) __bf16 bf16x4;
typedef __attribute__((ext_vector_type(4))) float f32x4;

// ---------------- K1: embedding bag sum -> L2 normalize -> +bias -> relu ----
__global__ void k_query(const int* __restrict__ x, const float* __restrict__ emb,
                        const float* __restrict__ bias, float* __restrict__ qf,
                        bf16_t* __restrict__ qb) {
    const int row = blockIdx.x;
    const int t = threadIdx.x; // 128 threads, one per dim
    __shared__ int sidx[TFEAT];
    if (t < TFEAT) sidx[t] = x[row * TFEAT + t];
    __syncthreads();
    float s = 0.f;
    #pragma unroll 10
    for (int i = 0; i < TFEAT; ++i) {
        s += emb[(size_t)sidx[i] * DDIM + t];
    }
    float sq = s * s;
    #pragma unroll
    for (int off = 1; off < 64; off <<= 1) sq += __shfl_xor(sq, off, 64);
    __shared__ float wred[2];
    if ((threadIdx.x & 63) == 0) wred[threadIdx.x >> 6] = sq;
    __syncthreads();
    const float tot = wred[0] + wred[1];
    float q = s / sqrtf(tot) + bias[t];
    q = fmaxf(q, 0.f);
    qf[row * DDIM + t] = q;
    qb[row * DDIM + t] = (bf16_t)q;
}

// ---------------- K2: MFMA logits + per-block partial sum-of-exp ------------
// R3-proven pipeline (90.7us): stage global->regs (coalesced dwordx4), cvt to
// bf16 in-reg, ds_write into 2x16KB XOR-swizzled bf16 double buffer;
// convwrite's dataflow vmcnt waits are the only load waits; __syncthreads is
// drain-free (nothing in flight at it); next chunk's loads issued right after
// the barrier fly across the whole compute phase.
// THIS ROUND (clean A/B vs R5): identical body to R5's diet (nt-outer acc[4],
// exp2-prescale consume) but launch_bounds(256,2) — NO forced register cap
// (R5 lesson: squeezing the allocator melts down). Natural usage ~155-165
// VGPR <= 170 -> 3 blocks/CU resident with NBLK=768: 3 anti-phased chunk
// streams per CU hide the depth-1 prefetch stall.
__global__ __launch_bounds__(256, 2)
void k_lse(const float* __restrict__ W, const float* __restrict__ b_out,
           const bf16_t* __restrict__ qb, float* __restrict__ partials) {
    __shared__ bf16_t lds[2][64 * DDIM]; // 2 x 16 KB bf16
    const int tid = threadIdx.x;
    const int lane = tid & 63;
    const int w = tid >> 6;
    const int l15 = lane & 15;
    const int l4 = lane >> 4;

    // A fragments: this wave's 64 batch rows (constant for whole kernel)
    bf16x8 a[4][4];
    #pragma unroll
    for (int mt = 0; mt < 4; ++mt)
        #pragma unroll
        for (int ks = 0; ks < 4; ++ks)
            a[mt][ks] = *(const bf16x8*)(qb + (w * 64 + mt * 16 + l15) * DDIM + ks * 32 + 8 * l4);

    float rs[4][4];
    #pragma unroll
    for (int mt = 0; mt < 4; ++mt)
        #pragma unroll
        for (int r = 0; r < 4; ++r) rs[mt][r] = 0.f;

    // staging geometry: thread covers f32 elems (row = j*8 + tid>>5,
    // cols [(tid&31)*4, +4)); global access per j = contiguous 1KB/wave.
    const int srow = tid >> 5;
    const int scol = (tid & 31) * 4;
    const int c16  = (tid & 31) >> 1;  // dest 16B slot within row
    const int half = (tid & 1) * 4;    // bf16 offset within slot

    f32x4 wr[8];
    float bo_n[4];

    auto issue = [&](int ch) {
        const int cb = ch * 64;
        #pragma unroll
        for (int j = 0; j < 8; ++j) {
            int r = cb + j * 8 + srow;
            r = (r < OUT_DIMX) ? r : 0; // clamp: unconditional, in-bounds
            wr[j] = *(const f32x4*)(W + (size_t)r * DDIM + scol);
        }
        #pragma unroll
        for (int nt = 0; nt < 4; ++nt) {
            int cc = cb + nt * 16 + l15;
            cc = (cc < OUT_DIMX) ? cc : 0;
            bo_n[nt] = b_out[cc] * LOG2E; // pre-scaled for exp2 consume
        }
    };

    auto convwrite = [&](int cur) {
        #pragma unroll
        for (int j = 0; j < 8; ++j) {
            const int row = j * 8 + srow;
            const int sp = row * 16 + (c16 ^ (row & 7));
            bf16x4 v;
            v[0] = (bf16_t)wr[j][0]; v[1] = (bf16_t)wr[j][1];
            v[2] = (bf16_t)wr[j][2]; v[3] = (bf16_t)wr[j][3];
            *(bf16x4*)(&lds[cur][sp * 8 + half]) = v;
        }
    };

    int cur = 0;
    issue(blockIdx.x);
    for (int ch = blockIdx.x; ch < NCHUNK; ch += NBLK) {
        float bo_c[4];
        #pragma unroll
        for (int nt = 0; nt < 4; ++nt) bo_c[nt] = bo_n[nt];

        convwrite(cur);          // waits wr's vmcnt incrementally
        __syncthreads();         // nothing in flight -> drain-free barrier
        __builtin_amdgcn_sched_barrier(0);
        if (ch + NBLK < NCHUNK) issue(ch + NBLK); // flies across compute

        const int cbase = ch * 64;
        if (cbase + 64 <= OUT_DIMX) { // full chunk: no masking
            #pragma unroll
            for (int nt = 0; nt < 4; ++nt) {
                f32x4 acc[4];
                #pragma unroll
                for (int mt = 0; mt < 4; ++mt) acc[mt] = (f32x4){0.f, 0.f, 0.f, 0.f};
                const int row = nt * 16 + l15;
                #pragma unroll
                for (int ks = 0; ks < 4; ++ks) {
                    const int sp = row * 16 + ((ks * 4 + l4) ^ (row & 7));
                    const bf16x8 b = *(const bf16x8*)(&lds[cur][sp * 8]);
                    #pragma unroll
                    for (int mt = 0; mt < 4; ++mt)
                        acc[mt] = __builtin_amdgcn_mfma_f32_16x16x32_bf16(
                            a[mt][ks], b, acc[mt], 0, 0, 0);
                }
                #pragma unroll
                for (int mt = 0; mt < 4; ++mt)
                    #pragma unroll
                    for (int r = 0; r < 4; ++r)
                        rs[mt][r] += exp2f(fmaf(acc[mt][r], LOG2E, bo_c[nt]));
            }
        } else { // single partial tail chunk
            #pragma unroll
            for (int nt = 0; nt < 4; ++nt) {
                f32x4 acc[4];
                #pragma unroll
                for (int mt = 0; mt < 4; ++mt) acc[mt] = (f32x4){0.f, 0.f, 0.f, 0.f};
                const int row = nt * 16 + l15;
                #pragma unroll
                for (int ks = 0; ks < 4; ++ks) {
                    const int sp = row * 16 + ((ks * 4 + l4) ^ (row & 7));
                    const bf16x8 b = *(const bf16x8*)(&lds[cur][sp * 8]);
                    #pragma unroll
                    for (int mt = 0; mt < 4; ++mt)
                        acc[mt] = __builtin_amdgcn_mfma_f32_16x16x32_bf16(
                            a[mt][ks], b, acc[mt], 0, 0, 0);
                }
                const bool valid = (cbase + nt * 16 + l15 < OUT_DIMX);
                #pragma unroll
                for (int mt = 0; mt < 4; ++mt)
                    #pragma unroll
                    for (int r = 0; r < 4; ++r)
                        rs[mt][r] += valid ? exp2f(fmaf(acc[mt][r], LOG2E, bo_c[nt])) : 0.f;
            }
        }
        cur ^= 1;
    }

    // reduce across the 16 lanes sharing each batch row; transposed layout
    // partials[row * NBLK + blk] so k_rowlse reads coalesced.
    #pragma unroll
    for (int mt = 0; mt < 4; ++mt)
        #pragma unroll
        for (int r = 0; r < 4; ++r) {
            float v = rs[mt][r];
            v += __shfl_xor(v, 1, 64);
            v += __shfl_xor(v, 2, 64);
            v += __shfl_xor(v, 4, 64);
            v += __shfl_xor(v, 8, 64);
            if (l15 == 0) {
                const int rowb = w * 64 + mt * 16 + l4 * 4 + r;
                partials[(size_t)rowb * NBLK + blockIdx.x] = v;
            }
        }
}

// ---------------- K3: per-row logsumexp + label logit -> per-row loss -------
__global__ void k_rowlse(const float* __restrict__ partials,
                         const int* __restrict__ y,
                         const float* __restrict__ qf,
                         const float* __restrict__ W,
                         const float* __restrict__ b_out,
                         float* __restrict__ rowloss) {
    const int i = blockIdx.x;     // batch row
    const int lane = threadIdx.x; // 64
    float s = 0.f;
    #pragma unroll
    for (int k = 0; k < NBLK / 64; ++k)
        s += partials[(size_t)i * NBLK + k * 64 + lane];
    // label logit: dot(q_i, W[y_i]) fused here
    const int yi = y[i];
    const float* wrow = W + (size_t)yi * DDIM;
    const float* qrow = qf + i * DDIM;
    float d = qrow[lane] * wrow[lane] + qrow[lane + 64] * wrow[lane + 64];
    #pragma unroll
    for (int off = 1; off < 64; off <<= 1) {
        s += __shfl_xor(s, off, 64);
        d += __shfl_xor(d, off, 64);
    }
    if (lane == 0) rowloss[i] = logf(s) - (d + b_out[yi]);
}

// ---------------- K4: mean over batch -> scalar loss ------------------------
__global__ void k_final(const float* __restrict__ rowloss, float* __restrict__ out) {
    const int i = threadIdx.x; // 256
    float t = rowloss[i];
    #pragma unroll
    for (int off = 1; off < 64; off <<= 1) t += __shfl_xor(t, off, 64);
    __shared__ float wred[4];
    if ((threadIdx.x & 63) == 0) wred[threadIdx.x >> 6] = t;
    __syncthreads();
    if (threadIdx.x == 0)
        out[0] = (wred[0] + wred[1] + wred[2] + wred[3]) * (1.0f / (float)BATCH);
}

extern "C" void kernel_launch(void* const* d_in, const int* in_sizes, int n_in,
                              void* d_out, int out_size, void* d_ws, size_t ws_size,
                              hipStream_t stream) {
    const int*   x     = (const int*)d_in[0];
    const int*   y     = (const int*)d_in[1];
    // d_in[2] = freeze, d_in[3] = slide (unused: exact/full softmax path)
    const float* emb   = (const float*)d_in[4];
    const float* bias  = (const float*)d_in[5];
    const float* W     = (const float*)d_in[6];
    const float* b_out = (const float*)d_in[7];
    float* out = (float*)d_out;

    char* ws = (char*)d_ws;
    bf16_t* qb       = (bf16_t*)(ws);           // 256*128*2 = 64 KB
    float*  qf       = (float*)(ws + 65536);    // 256*128*4 = 128 KB
    float*  rowloss  = (float*)(ws + 197632);   // 1 KB
    float*  partials = (float*)(ws + 262144);   // 256*NBLK*4 = 768 KB

    k_query<<<BATCH, DDIM, 0, stream>>>(x, emb, bias, qf, qb);
    k_lse<<<NBLK, 256, 0, stream>>>(W, b_out, qb, partials);
    k_rowlse<<<BATCH, 64, 0, stream>>>(partials, y, qf, W, b_out, rowloss);
    k_final<<<1, 256, 0, stream>>>(rowloss, out);
}

// Round 8
// 89.001 us; speedup vs baseline: 1.2466x; 1.2466x over previous
//
#include <hip/hip_runtime.h>
#include <hip/hip_bf16.h>

#define IN_DIMX 135909
#define OUT_DIMX 670091
#define DDIM 128
#define BATCH 256
#define TFEAT 100
#define NBLK 512                      // k_lse grid: 2 blocks/CU resident
#define NCHUNK ((OUT_DIMX + 63) / 64) // 10471 chunks of 64 classes

typedef __bf16 bf16_t;
typedef __attribute__((ext_vector_type(8))) __bf16 bf16x8;
typedef __attribute__((ext_vector_type(4))) __bf16 bf16x4;
typedef __attribute__((ext_vector_type(4))) float f32x4;

// ---------------- K1: embedding bag sum -> L2 normalize -> +bias -> relu ----
__global__ void k_query(const int* __restrict__ x, const float* __restrict__ emb,
                        const float* __restrict__ bias, float* __restrict__ qf,
                        bf16_t* __restrict__ qb) {
    const int row = blockIdx.x;
    const int t = threadIdx.x; // 128 threads, one per dim
    __shared__ int sidx[TFEAT];
    if (t < TFEAT) sidx[t] = x[row * TFEAT + t];
    __syncthreads();
    float s = 0.f;
    #pragma unroll 10
    for (int i = 0; i < TFEAT; ++i) {
        s += emb[(size_t)sidx[i] * DDIM + t];
    }
    float sq = s * s;
    #pragma unroll
    for (int off = 1; off < 64; off <<= 1) sq += __shfl_xor(sq, off, 64);
    __shared__ float wred[2];
    if ((threadIdx.x & 63) == 0) wred[threadIdx.x >> 6] = sq;
    __syncthreads();
    const float tot = wred[0] + wred[1];
    float q = s / sqrtf(tot) + bias[t];
    q = fmaxf(q, 0.f);
    qf[row * DDIM + t] = q;
    qb[row * DDIM + t] = (bf16_t)q;
}

// ---------------- K2: MFMA logits + per-block partial sum-of-exp ------------
// R3 body (proven 90.7us) with ONE change: fused convwrite+reload (wr[j]
// reused in place, zero extra registers) + RAW barrier (lgkmcnt(0) only, no
// vmcnt drain) so the next chunk's 8 loads are issued BEFORE the barrier and
// stay in flight across it -> no request-free HBM window per chunk.
// Safety: lds writes lgkm-waited before s_barrier; loads write only the
// issuing wave's own regs; one barrier per chunk separates lds[cur] last-read
// from its next overwrite (same parity as R3).
__global__ __launch_bounds__(256, 2)
void k_lse(const float* __restrict__ W, const float* __restrict__ b_out,
           const bf16_t* __restrict__ qb, float* __restrict__ partials) {
    __shared__ bf16_t lds[2][64 * DDIM]; // 2 x 16 KB bf16
    const int tid = threadIdx.x;
    const int lane = tid & 63;
    const int w = tid >> 6;
    const int l15 = lane & 15;
    const int l4 = lane >> 4;

    // A fragments: this wave's 64 batch rows (constant for whole kernel)
    bf16x8 a[4][4];
    #pragma unroll
    for (int mt = 0; mt < 4; ++mt)
        #pragma unroll
        for (int ks = 0; ks < 4; ++ks)
            a[mt][ks] = *(const bf16x8*)(qb + (w * 64 + mt * 16 + l15) * DDIM + ks * 32 + 8 * l4);

    float rs[4][4];
    #pragma unroll
    for (int mt = 0; mt < 4; ++mt)
        #pragma unroll
        for (int r = 0; r < 4; ++r) rs[mt][r] = 0.f;

    // staging geometry: thread covers f32 elems (row = j*8 + tid>>5,
    // cols [(tid&31)*4, +4)); global access per j = contiguous 1KB/wave.
    const int srow = tid >> 5;
    const int scol = (tid & 31) * 4;
    const int c16  = (tid & 31) >> 1;  // dest 16B slot within row
    const int half = (tid & 1) * 4;    // bf16 offset within slot

    f32x4 wr[8];
    float bo_n[4];

    auto issue = [&](int ch) {
        const int cb = ch * 64;
        #pragma unroll
        for (int j = 0; j < 8; ++j) {
            int r = cb + j * 8 + srow;
            r = (r < OUT_DIMX) ? r : 0; // clamp: unconditional, in-bounds
            wr[j] = *(const f32x4*)(W + (size_t)r * DDIM + scol);
        }
        #pragma unroll
        for (int nt = 0; nt < 4; ++nt) {
            int cc = cb + nt * 16 + l15;
            cc = (cc < OUT_DIMX) ? cc : 0;
            bo_n[nt] = b_out[cc];
        }
    };

    // Fused: for each j, convert+ds_write wr[j] then immediately reload wr[j]
    // with the next chunk's row j. Loads issue interleaved with ds_writes,
    // BEFORE the barrier, and ride across it (raw barrier, no vmcnt drain).
    auto convwrite_reload = [&](int cur, bool has_next, int nch) {
        const int cb = nch * 64;
        #pragma unroll
        for (int j = 0; j < 8; ++j) {
            const int row = j * 8 + srow;
            const int sp = row * 16 + (c16 ^ (row & 7));
            bf16x4 v;
            v[0] = (bf16_t)wr[j][0]; v[1] = (bf16_t)wr[j][1];
            v[2] = (bf16_t)wr[j][2]; v[3] = (bf16_t)wr[j][3];
            *(bf16x4*)(&lds[cur][sp * 8 + half]) = v;
            if (has_next) {
                int r = cb + j * 8 + srow;
                r = (r < OUT_DIMX) ? r : 0;
                wr[j] = *(const f32x4*)(W + (size_t)r * DDIM + scol);
            }
        }
    };

    int cur = 0;
    issue(blockIdx.x);
    for (int ch = blockIdx.x; ch < NCHUNK; ch += NBLK) {
        float bo_c[4];
        #pragma unroll
        for (int nt = 0; nt < 4; ++nt) bo_c[nt] = bo_n[nt];

        const bool has_next = (ch + NBLK < NCHUNK);
        convwrite_reload(cur, has_next, has_next ? ch + NBLK : 0);
        if (has_next) { // next chunk's b_out (tiny, rides with the W loads)
            const int cb = (ch + NBLK) * 64;
            #pragma unroll
            for (int nt = 0; nt < 4; ++nt) {
                int cc = cb + nt * 16 + l15;
                cc = (cc < OUT_DIMX) ? cc : 0;
                bo_n[nt] = b_out[cc];
            }
        }
        // RAW barrier: wait only LDS writes; W loads stay in flight across it.
        asm volatile("s_waitcnt lgkmcnt(0)" ::: "memory");
        __builtin_amdgcn_s_barrier();
        asm volatile("" ::: "memory"); // compiler fence: no ds_read hoist above barrier

        f32x4 acc[4][4];
        #pragma unroll
        for (int mt = 0; mt < 4; ++mt)
            #pragma unroll
            for (int nt = 0; nt < 4; ++nt) acc[mt][nt] = (f32x4){0.f, 0.f, 0.f, 0.f};

        #pragma unroll
        for (int ks = 0; ks < 4; ++ks) {
            #pragma unroll
            for (int nt = 0; nt < 4; ++nt) {
                const int row = nt * 16 + l15;
                const int sp = row * 16 + ((ks * 4 + l4) ^ (row & 7));
                const bf16x8 b = *(const bf16x8*)(&lds[cur][sp * 8]);
                #pragma unroll
                for (int mt = 0; mt < 4; ++mt)
                    acc[mt][nt] = __builtin_amdgcn_mfma_f32_16x16x32_bf16(
                        a[mt][ks], b, acc[mt][nt], 0, 0, 0);
            }
        }

        const int cbase = ch * 64;
        if (cbase + 64 <= OUT_DIMX) { // full chunk: no masking
            #pragma unroll
            for (int nt = 0; nt < 4; ++nt)
                #pragma unroll
                for (int mt = 0; mt < 4; ++mt)
                    #pragma unroll
                    for (int r = 0; r < 4; ++r)
                        rs[mt][r] += __expf(acc[mt][nt][r] + bo_c[nt]);
        } else { // single partial tail chunk
            #pragma unroll
            for (int nt = 0; nt < 4; ++nt) {
                const bool valid = (cbase + nt * 16 + l15 < OUT_DIMX);
                #pragma unroll
                for (int mt = 0; mt < 4; ++mt)
                    #pragma unroll
                    for (int r = 0; r < 4; ++r)
                        rs[mt][r] += valid ? __expf(acc[mt][nt][r] + bo_c[nt]) : 0.f;
            }
        }
        cur ^= 1;
    }

    // reduce across the 16 lanes sharing each batch row; transposed layout
    // partials[row * NBLK + blk] so k_rowlse reads coalesced.
    #pragma unroll
    for (int mt = 0; mt < 4; ++mt)
        #pragma unroll
        for (int r = 0; r < 4; ++r) {
            float v = rs[mt][r];
            v += __shfl_xor(v, 1, 64);
            v += __shfl_xor(v, 2, 64);
            v += __shfl_xor(v, 4, 64);
            v += __shfl_xor(v, 8, 64);
            if (l15 == 0) {
                const int rowb = w * 64 + mt * 16 + l4 * 4 + r;
                partials[(size_t)rowb * NBLK + blockIdx.x] = v;
            }
        }
}

// ---------------- K3: per-row logsumexp + label logit -> per-row loss -------
__global__ void k_rowlse(const float* __restrict__ partials,
                         const int* __restrict__ y,
                         const float* __restrict__ qf,
                         const float* __restrict__ W,
                         const float* __restrict__ b_out,
                         float* __restrict__ rowloss) {
    const int i = blockIdx.x;     // batch row
    const int lane = threadIdx.x; // 64
    float s = 0.f;
    #pragma unroll
    for (int k = 0; k < NBLK / 64; ++k)
        s += partials[(size_t)i * NBLK + k * 64 + lane];
    // label logit: dot(q_i, W[y_i]) fused here
    const int yi = y[i];
    const float* wrow = W + (size_t)yi * DDIM;
    const float* qrow = qf + i * DDIM;
    float d = qrow[lane] * wrow[lane] + qrow[lane + 64] * wrow[lane + 64];
    #pragma unroll
    for (int off = 1; off < 64; off <<= 1) {
        s += __shfl_xor(s, off, 64);
        d += __shfl_xor(d, off, 64);
    }
    if (lane == 0) rowloss[i] = logf(s) - (d + b_out[yi]);
}

// ---------------- K4: mean over batch -> scalar loss ------------------------
__global__ void k_final(const float* __restrict__ rowloss, float* __restrict__ out) {
    const int i = threadIdx.x; // 256
    float t = rowloss[i];
    #pragma unroll
    for (int off = 1; off < 64; off <<= 1) t += __shfl_xor(t, off, 64);
    __shared__ float wred[4];
    if ((threadIdx.x & 63) == 0) wred[threadIdx.x >> 6] = t;
    __syncthreads();
    if (threadIdx.x == 0)
        out[0] = (wred[0] + wred[1] + wred[2] + wred[3]) * (1.0f / (float)BATCH);
}

extern "C" void kernel_launch(void* const* d_in, const int* in_sizes, int n_in,
                              void* d_out, int out_size, void* d_ws, size_t ws_size,
                              hipStream_t stream) {
    const int*   x     = (const int*)d_in[0];
    const int*   y     = (const int*)d_in[1];
    // d_in[2] = freeze, d_in[3] = slide (unused: exact/full softmax path)
    const float* emb   = (const float*)d_in[4];
    const float* bias  = (const float*)d_in[5];
    const float* W     = (const float*)d_in[6];
    const float* b_out = (const float*)d_in[7];
    float* out = (float*)d_out;

    char* ws = (char*)d_ws;
    bf16_t* qb       = (bf16_t*)(ws);           // 256*128*2 = 64 KB
    float*  qf       = (float*)(ws + 65536);    // 256*128*4 = 128 KB
    float*  rowloss  = (float*)(ws + 197632);   // 1 KB
    float*  partials = (float*)(ws + 262144);   // 256*NBLK*4 = 512 KB

    k_query<<<BATCH, DDIM, 0, stream>>>(x, emb, bias, qf, qb);
    k_lse<<<NBLK, 256, 0, stream>>>(W, b_out, qb, partials);
    k_rowlse<<<BATCH, 64, 0, stream>>>(partials, y, qf, W, b_out, rowloss);
    k_final<<<1, 256, 0, stream>>>(rowloss, out);
}